// Round 2
// baseline (107.259 us; speedup 1.0000x reference)
//
#include <hip/hip_runtime.h>
#include <math.h>

// A3C batch-1 forward, R14: remove the H3 hop too.
//
// R13 (102.3us) removed the H4 hop by computing h4 redundantly in G
// (w4 full in regs). R14 applies the same pattern to h3: team C is
// deleted; each G block holds ALL of w3 in registers (32 f4/thread =
// 128 VGPR) in addition to w4 (16 f4) + w_hh/w_ih slices (8+8 f4),
// ~300 VGPR total — under the 450 no-spill boundary at 1 wave/SIMD.
// G recvs H2 directly and computes h3 (128 rows, 2 thr/row), then h4,
// gates, LSTM, heads. Chain: H2 -> PT = 2 hops (was 3).
// Also: steady-state poll sleep 8 -> 4 (halve wake quantization).
//
// Teams (TPB=256, NB=24):
//   B: blk 0..15  h1 redundant (W1 30KB first) + 16 h2 rows -> send H2
//   G: blk 16..23 w3+w4 full in regs + 16 LSTM cells (64 gate rows,
//                 w_hh early for g0); recv H2 -> h3 (redundant 128) ->
//                 h4 (redundant 128) -> gates -> LSTM(16) -> 7 head
//                 partials; G0 reduces 8x7, softsign, writes out.

#define NB   24
#define TPB  256
#define MAGIC 0x3A3C5A17u

#define H2_OFF 0      // 256 pairs (16 lines)
#define H3_OFF 256    // (unused in R14)
#define H4_OFF 384    // (unused)
#define PT_OFF 512    // 8 lines; G block g owns pairs [g*8 .. g*8+6]

__device__ __forceinline__ float lrelu(float v) { return v > 0.f ? v : 0.1f * v; }
__device__ __forceinline__ float sigm(float v)  { return 1.f / (1.f + __expf(-v)); }
__device__ __forceinline__ float dot4(float4 a, float4 b) {
    return a.x * b.x + a.y * b.y + a.z * b.z + a.w * b.w;
}

__device__ __forceinline__ void send(unsigned long long* p, float v) {
    unsigned lo = __float_as_uint(v);
    unsigned long long pk = (unsigned long long)lo |
                            ((unsigned long long)(lo ^ MAGIC) << 32);
    __hip_atomic_store(p, pk, __ATOMIC_RELAXED, __HIP_MEMORY_SCOPE_AGENT);
}
__device__ __forceinline__ float recv(unsigned long long* p) {
    unsigned long long pk =
        __hip_atomic_load(p, __ATOMIC_RELAXED, __HIP_MEMORY_SCOPE_AGENT);
    unsigned lo = (unsigned)pk, hi = (unsigned)(pk >> 32);
    if ((lo ^ MAGIC) == hi) return __uint_as_float(lo);
    __builtin_amdgcn_s_sleep(2);
    for (;;) {
        pk = __hip_atomic_load(p, __ATOMIC_RELAXED, __HIP_MEMORY_SCOPE_AGENT);
        lo = (unsigned)pk; hi = (unsigned)(pk >> 32);
        if ((lo ^ MAGIC) == hi) return __uint_as_float(lo);
        __builtin_amdgcn_s_sleep(4);
    }
}
__device__ __forceinline__ void touch(unsigned long long* p) {
    unsigned long long v =
        __hip_atomic_load(p, __ATOMIC_RELAXED, __HIP_MEMORY_SCOPE_AGENT);
    asm volatile("" :: "v"(v));
}

__global__ __launch_bounds__(TPB, 1) void a3c_fwd(
    const float* __restrict__ x, const float* __restrict__ hx, const float* __restrict__ cx,
    const float* __restrict__ w1, const float* __restrict__ b1,
    const float* __restrict__ w2, const float* __restrict__ b2,
    const float* __restrict__ w3, const float* __restrict__ b3,
    const float* __restrict__ w4, const float* __restrict__ b4,
    const float* __restrict__ w_ih, const float* __restrict__ b_ih,
    const float* __restrict__ w_hh, const float* __restrict__ b_hh,
    const float* __restrict__ w_critic, const float* __restrict__ b_critic,
    const float* __restrict__ w_actor, const float* __restrict__ b_actor,
    const float* __restrict__ w_actor2, const float* __restrict__ b_actor2,
    float* __restrict__ out, unsigned long long* __restrict__ wsp)
{
    const int blk = blockIdx.x, tid = threadIdx.x;

    if (blk < 16) {
        // ---- Team B: h1 (redundant, W1 first) + 16 h2 rows (unchanged) ----
        const int b = blk;
        if (tid == 0) touch(wsp + H2_OFF + b * 16);
        if (tid == 1) touch(wsp + H2_OFF + b * 16 + 8);

        float a1[29];
        {
            const float* w1r = w1 + tid * 29;
            #pragma unroll
            for (int j = 0; j < 29; ++j) a1[j] = w1r[j];
        }
        const float bb1 = b1[tid];

        const int r2 = b * 16 + (tid >> 4), p2 = tid & 15;
        float4 a2[4];
        {
            const float4* wp = (const float4*)(w2 + r2 * 256 + p2 * 16);
            #pragma unroll
            for (int j = 0; j < 4; ++j) a2[j] = wp[j];
        }
        const float bb2 = b2[r2];

        __shared__ __align__(16) float x_s[32];
        __shared__ __align__(16) float h1_s[256];
        if (tid < 32) x_s[tid] = (tid < 29) ? x[tid] : 0.f;
        __syncthreads();

        {
            float s = 0.f;
            #pragma unroll
            for (int j = 0; j < 29; ++j) s += a1[j] * x_s[j];
            h1_s[tid] = lrelu(s + bb1);
        }
        __syncthreads();

        {
            const float4* hp = (const float4*)(h1_s + p2 * 16);
            float s = 0.f;
            #pragma unroll
            for (int j = 0; j < 4; ++j) s += dot4(a2[j], hp[j]);
            s += __shfl_xor(s, 1); s += __shfl_xor(s, 2);
            s += __shfl_xor(s, 4); s += __shfl_xor(s, 8);
            if (p2 == 0) send(wsp + H2_OFF + r2, lrelu(s + bb2));
        }
        return;
    }

    // ---- Team G: w3+w4 full + 16 LSTM cells/blk; recv H2 -> h3 -> h4 ->
    //      gates -> LSTM -> heads; epilogue on G0 ----
    {
        const int g = blk - 16;                       // [0,8)
        if (tid < 16) touch(wsp + H2_OFF + tid * 16); // recv set (H2 now)
        if (g > 0) { if (tid == 16) touch(wsp + PT_OFF + g * 8); }
        else       { if (tid >= 17 && tid < 24) touch(wsp + PT_OFF + (tid - 16) * 8); }

        // w3 full: 128 rows x 2 lanes x 128 cols. Needed first after H2.
        const int r3 = tid >> 1, p3 = tid & 1;
        float4 a3[32];
        {
            const float4* wp = (const float4*)(w3 + r3 * 256 + p3 * 128);
            #pragma unroll
            for (int j = 0; j < 32; ++j) a3[j] = wp[j];
        }
        const float bb3 = b3[r3];

        // w4 full: 128 rows x 2 lanes x 64 cols. Needed second.
        const int r4 = tid >> 1, p4 = tid & 1;
        float4 a4[16];
        {
            const float4* wp = (const float4*)(w4 + r4 * 128 + p4 * 64);
            #pragma unroll
            for (int j = 0; j < 16; ++j) a4[j] = wp[j];
        }
        const float bb4 = b4[r4];

        const int r = tid >> 2, p = tid & 3;          // 64 rows x 4 lanes x 32
        const int gate = r >> 4, cell = r & 15;
        const int grow = gate * 128 + g * 16 + cell;

        float4 ah[8];
        {
            const float4* wp = (const float4*)(w_hh + grow * 128 + p * 32);
            #pragma unroll
            for (int j = 0; j < 8; ++j) ah[j] = wp[j];
        }
        float4 ai[8];
        {
            const float4* wp = (const float4*)(w_ih + grow * 128 + p * 32);
            #pragma unroll
            for (int j = 0; j < 8; ++j) ai[j] = wp[j];
        }
        const float bsum = b_ih[grow] + b_hh[grow];

        __shared__ __align__(16) float hx_s[128];
        __shared__ __align__(16) float h2_s[256];
        __shared__ __align__(16) float h3_s[128];
        __shared__ __align__(16) float h4_s[128];
        __shared__ __align__(16) float g_s[64];
        __shared__ __align__(16) float hn_s[16];
        __shared__ __align__(16) float hw_s[112];   // 7 heads x 16 cells
        __shared__ __align__(16) float hb_s[8];
        __shared__ __align__(16) float ps[64];      // G0: 7 heads x 8 blocks

        if (tid < 128) hx_s[tid] = hx[tid];
        float cxv = (tid < 16) ? cx[g * 16 + tid] : 0.f;
        if (tid < 112) {
            int o = tid >> 4, c = tid & 15;
            float v;
            if (o == 0)      v = w_critic[g * 16 + c];
            else if (o < 4)  v = w_actor [(o - 1) * 128 + g * 16 + c];
            else             v = w_actor2[(o - 4) * 128 + g * 16 + c];
            hw_s[tid] = v;
        }
        if (g == 0 && tid == 0) {
            hb_s[0] = b_critic[0];
            hb_s[1] = b_actor[0];  hb_s[2] = b_actor[1];  hb_s[3] = b_actor[2];
            hb_s[4] = b_actor2[0]; hb_s[5] = b_actor2[1]; hb_s[6] = b_actor2[2];
        }
        __syncthreads();

        // g0 = W_hh @ hx + biases (off critical path, during H2 wait)
        float g0;
        {
            const float4* hp = (const float4*)(hx_s + p * 32);
            float s = 0.f;
            #pragma unroll
            for (int j = 0; j < 8; ++j) s += dot4(ah[j], hp[j]);
            s += __shfl_xor(s, 1); s += __shfl_xor(s, 2);
            g0 = s + bsum;
        }

        if (tid < 256) h2_s[tid] = recv(wsp + H2_OFF + tid);
        __syncthreads();

        { // h3: all 128 rows, redundant per G block (kills the H3 hop).
          // h2_s read is 2-address broadcast across the wave (conflict-free).
            const float4* hp = (const float4*)(h2_s + p3 * 128);
            float s = 0.f;
            #pragma unroll
            for (int j = 0; j < 32; ++j) s += dot4(a3[j], hp[j]);
            s += __shfl_xor(s, 1);
            if (p3 == 0) h3_s[r3] = lrelu(s + bb3);
        }
        __syncthreads();

        { // h4: all 128 rows, redundant per G block
            const float4* hp = (const float4*)(h3_s + p4 * 64);
            float s = 0.f;
            #pragma unroll
            for (int j = 0; j < 16; ++j) s += dot4(a4[j], hp[j]);
            s += __shfl_xor(s, 1);
            if (p4 == 0) h4_s[r4] = lrelu(s + bb4);
        }
        __syncthreads();

        { // gates for 64 rows
            const float4* hp = (const float4*)(h4_s + p * 32);
            float s = 0.f;
            #pragma unroll
            for (int j = 0; j < 8; ++j) s += dot4(ai[j], hp[j]);
            s += __shfl_xor(s, 1); s += __shfl_xor(s, 2);
            if (p == 0) g_s[r] = g0 + s;   // r = gate*16 + cell
        }
        __syncthreads();

        if (tid < 16) {   // LSTM elementwise, 16 cells
            float ig = g_s[tid];
            float fg = g_s[16 + tid];
            float gg = g_s[32 + tid];
            float og = g_s[48 + tid];
            float c  = sigm(fg) * cxv + sigm(ig) * tanhf(gg);
            hn_s[tid] = sigm(og) * tanhf(c);
        }
        __syncthreads();

        if (tid < 7) {    // 7 head partials over this block's 16 cells
            const float* wc = hw_s + tid * 16;
            float s = 0.f;
            #pragma unroll
            for (int j = 0; j < 16; ++j) s += wc[j] * hn_s[j];
            if (g > 0) send(wsp + PT_OFF + g * 8 + tid, s);
            else       ps[tid * 8] = s + hb_s[tid];
        }

        if (g == 0) {
            if (tid < 56) {
                const int gg = (tid >> 3) + 1, h = tid & 7;
                if (h < 7) ps[h * 8 + gg] = recv(wsp + PT_OFF + gg * 8 + h);
            }
            __syncthreads();
            if (tid < 7) {
                const float* row = ps + tid * 8;
                float s = row[0] + row[1] + row[2] + row[3]
                        + row[4] + row[5] + row[6] + row[7];
                if (tid >= 1 && tid <= 3) s = s / (1.f + fabsf(s));
                out[tid] = s;
            }
        }
    }
}

extern "C" void kernel_launch(void* const* d_in, const int* in_sizes, int n_in,
                              void* d_out, int out_size, void* d_ws, size_t ws_size,
                              hipStream_t stream) {
    const float* x        = (const float*)d_in[0];
    const float* hx       = (const float*)d_in[1];
    const float* cx       = (const float*)d_in[2];
    const float* w1       = (const float*)d_in[3];
    const float* b1       = (const float*)d_in[4];
    const float* w2       = (const float*)d_in[5];
    const float* b2       = (const float*)d_in[6];
    const float* w3       = (const float*)d_in[7];
    const float* b3       = (const float*)d_in[8];
    const float* w4       = (const float*)d_in[9];
    const float* b4       = (const float*)d_in[10];
    const float* w_ih     = (const float*)d_in[11];
    const float* b_ih     = (const float*)d_in[12];
    const float* w_hh     = (const float*)d_in[13];
    const float* b_hh     = (const float*)d_in[14];
    const float* w_critic = (const float*)d_in[15];
    const float* b_critic = (const float*)d_in[16];
    const float* w_actor  = (const float*)d_in[17];
    const float* b_actor  = (const float*)d_in[18];
    const float* w_actor2 = (const float*)d_in[19];
    const float* b_actor2 = (const float*)d_in[20];
    float* out = (float*)d_out;
    unsigned long long* wsp = (unsigned long long*)d_ws;

    a3c_fwd<<<NB, TPB, 0, stream>>>(x, hx, cx, w1, b1, w2, b2, w3, b3, w4, b4,
                                    w_ih, b_ih, w_hh, b_hh,
                                    w_critic, b_critic, w_actor, b_actor,
                                    w_actor2, b_actor2, out, wsp);
}

// Round 3
// 101.905 us; speedup vs baseline: 1.0525x; 1.0525x over previous
//
#include <hip/hip_runtime.h>
#include <math.h>

// A3C batch-1 forward, R15: revert to R13 structure + C send-line prewarm.
//
// R14 post-mortem: w3 full = 128KB (not 32KB as mis-modeled); G prologue
// grew 96->224KB and landed on the critical path (+4.9us). Rule: redundant
// compute only pays while the extra weight prologue hides under the hop
// wait (~64KB fits, 128KB does not).
//
// R15 = R13 (verified 102.3us) exactly, plus: team C touches its two H3
// send lines in the prologue (B touches H2 send lines, G touches its PT
// send line; C was the only producer missing the prewarm).
//
// Teams (TPB=256, NB=28), chain H2 -> H3 -> PT (3 hops):
//   B: blk 0..15  h1 redundant (W1 30KB first) + 16 h2 rows -> send H2
//   C: blk 16..19 recv H2 -> 32 h3 rows -> send H3
//   G: blk 20..27 w4 full (64KB) + 16 LSTM cells (64 gate rows, w_hh
//                 early for g0); recv H3 -> h4 (redundant 128 rows) ->
//                 gates -> LSTM(16) -> 7 head partials; G0 reduces 8x7.

#define NB   28
#define TPB  256
#define MAGIC 0x3A3C5A17u

#define H2_OFF 0      // 256 pairs (16 lines)
#define H3_OFF 256    // 128 pairs (8 lines)
#define H4_OFF 384    // (unused, layout stability)
#define PT_OFF 512    // 8 lines; G block g owns pairs [g*8 .. g*8+6]

__device__ __forceinline__ float lrelu(float v) { return v > 0.f ? v : 0.1f * v; }
__device__ __forceinline__ float sigm(float v)  { return 1.f / (1.f + __expf(-v)); }
__device__ __forceinline__ float dot4(float4 a, float4 b) {
    return a.x * b.x + a.y * b.y + a.z * b.z + a.w * b.w;
}

__device__ __forceinline__ void send(unsigned long long* p, float v) {
    unsigned lo = __float_as_uint(v);
    unsigned long long pk = (unsigned long long)lo |
                            ((unsigned long long)(lo ^ MAGIC) << 32);
    __hip_atomic_store(p, pk, __ATOMIC_RELAXED, __HIP_MEMORY_SCOPE_AGENT);
}
__device__ __forceinline__ float recv(unsigned long long* p) {
    unsigned long long pk =
        __hip_atomic_load(p, __ATOMIC_RELAXED, __HIP_MEMORY_SCOPE_AGENT);
    unsigned lo = (unsigned)pk, hi = (unsigned)(pk >> 32);
    if ((lo ^ MAGIC) == hi) return __uint_as_float(lo);
    __builtin_amdgcn_s_sleep(2);
    for (;;) {
        pk = __hip_atomic_load(p, __ATOMIC_RELAXED, __HIP_MEMORY_SCOPE_AGENT);
        lo = (unsigned)pk; hi = (unsigned)(pk >> 32);
        if ((lo ^ MAGIC) == hi) return __uint_as_float(lo);
        __builtin_amdgcn_s_sleep(8);
    }
}
__device__ __forceinline__ void touch(unsigned long long* p) {
    unsigned long long v =
        __hip_atomic_load(p, __ATOMIC_RELAXED, __HIP_MEMORY_SCOPE_AGENT);
    asm volatile("" :: "v"(v));
}

__global__ __launch_bounds__(TPB, 1) void a3c_fwd(
    const float* __restrict__ x, const float* __restrict__ hx, const float* __restrict__ cx,
    const float* __restrict__ w1, const float* __restrict__ b1,
    const float* __restrict__ w2, const float* __restrict__ b2,
    const float* __restrict__ w3, const float* __restrict__ b3,
    const float* __restrict__ w4, const float* __restrict__ b4,
    const float* __restrict__ w_ih, const float* __restrict__ b_ih,
    const float* __restrict__ w_hh, const float* __restrict__ b_hh,
    const float* __restrict__ w_critic, const float* __restrict__ b_critic,
    const float* __restrict__ w_actor, const float* __restrict__ b_actor,
    const float* __restrict__ w_actor2, const float* __restrict__ b_actor2,
    float* __restrict__ out, unsigned long long* __restrict__ wsp)
{
    const int blk = blockIdx.x, tid = threadIdx.x;

    if (blk < 16) {
        // ---- Team B: h1 (redundant, W1 first) + 16 h2 rows ----
        const int b = blk;
        if (tid == 0) touch(wsp + H2_OFF + b * 16);
        if (tid == 1) touch(wsp + H2_OFF + b * 16 + 8);

        float a1[29];
        {
            const float* w1r = w1 + tid * 29;
            #pragma unroll
            for (int j = 0; j < 29; ++j) a1[j] = w1r[j];
        }
        const float bb1 = b1[tid];

        const int r2 = b * 16 + (tid >> 4), p2 = tid & 15;
        float4 a2[4];
        {
            const float4* wp = (const float4*)(w2 + r2 * 256 + p2 * 16);
            #pragma unroll
            for (int j = 0; j < 4; ++j) a2[j] = wp[j];
        }
        const float bb2 = b2[r2];

        __shared__ __align__(16) float x_s[32];
        __shared__ __align__(16) float h1_s[256];
        if (tid < 32) x_s[tid] = (tid < 29) ? x[tid] : 0.f;
        __syncthreads();

        {
            float s = 0.f;
            #pragma unroll
            for (int j = 0; j < 29; ++j) s += a1[j] * x_s[j];
            h1_s[tid] = lrelu(s + bb1);
        }
        __syncthreads();

        {
            const float4* hp = (const float4*)(h1_s + p2 * 16);
            float s = 0.f;
            #pragma unroll
            for (int j = 0; j < 4; ++j) s += dot4(a2[j], hp[j]);
            s += __shfl_xor(s, 1); s += __shfl_xor(s, 2);
            s += __shfl_xor(s, 4); s += __shfl_xor(s, 8);
            if (p2 == 0) send(wsp + H2_OFF + r2, lrelu(s + bb2));
        }
        return;
    }

    if (blk < 20) {
        // ---- Team C: recv H2 -> 32 h3 rows -> send H3 ----
        const int c = blk - 16;
        if (tid < 16) touch(wsp + H2_OFF + tid * 16);
        // NEW in R15: prewarm own H3 send lines (2 lines: pairs c*32..c*32+31)
        else if (tid < 18) touch(wsp + H3_OFF + c * 32 + (tid - 16) * 16);

        const int r3 = c * 32 + (tid >> 3), p3 = tid & 7;   // 32 floats/lane
        float4 a3[8];
        {
            const float4* wp = (const float4*)(w3 + r3 * 256 + p3 * 32);
            #pragma unroll
            for (int j = 0; j < 8; ++j) a3[j] = wp[j];
        }
        const float bb3 = b3[r3];

        __shared__ __align__(16) float h2_s[256];
        h2_s[tid] = recv(wsp + H2_OFF + tid);
        __syncthreads();

        {
            const float4* hp = (const float4*)(h2_s + p3 * 32);
            float s = 0.f;
            #pragma unroll
            for (int j = 0; j < 8; ++j) s += dot4(a3[j], hp[j]);
            s += __shfl_xor(s, 1); s += __shfl_xor(s, 2); s += __shfl_xor(s, 4);
            if (p3 == 0) send(wsp + H3_OFF + r3, lrelu(s + bb3));
        }
        return;
    }

    // ---- Team G: w4 full + 16 LSTM cells/blk; recv H3 -> h4 redundant ->
    //      gates -> LSTM -> heads; epilogue on G0 ----
    {
        const int g = blk - 20;                       // [0,8)
        if (tid < 8) touch(wsp + H3_OFF + tid * 16);  // recv set (H3)
        if (g > 0) { if (tid == 8) touch(wsp + PT_OFF + g * 8); }
        else       { if (tid >= 9 && tid < 16) touch(wsp + PT_OFF + (tid - 8) * 8); }

        // w4 full: 128 rows x 2 lanes x 64 cols. Needed first after H3.
        const int r4 = tid >> 1, p4 = tid & 1;
        float4 a4[16];
        {
            const float4* wp = (const float4*)(w4 + r4 * 128 + p4 * 64);
            #pragma unroll
            for (int j = 0; j < 16; ++j) a4[j] = wp[j];
        }
        const float bb4 = b4[r4];

        const int r = tid >> 2, p = tid & 3;          // 64 rows x 4 lanes x 32
        const int gate = r >> 4, cell = r & 15;
        const int grow = gate * 128 + g * 16 + cell;

        float4 ah[8];
        {
            const float4* wp = (const float4*)(w_hh + grow * 128 + p * 32);
            #pragma unroll
            for (int j = 0; j < 8; ++j) ah[j] = wp[j];
        }
        float4 ai[8];
        {
            const float4* wp = (const float4*)(w_ih + grow * 128 + p * 32);
            #pragma unroll
            for (int j = 0; j < 8; ++j) ai[j] = wp[j];
        }
        const float bsum = b_ih[grow] + b_hh[grow];

        __shared__ __align__(16) float hx_s[128];
        __shared__ __align__(16) float h3_s[128];
        __shared__ __align__(16) float h4_s[128];
        __shared__ __align__(16) float g_s[64];
        __shared__ __align__(16) float hn_s[16];
        __shared__ __align__(16) float hw_s[112];   // 7 heads x 16 cells
        __shared__ __align__(16) float hb_s[8];
        __shared__ __align__(16) float ps[64];      // G0: 7 heads x 8 blocks

        if (tid < 128) hx_s[tid] = hx[tid];
        float cxv = (tid < 16) ? cx[g * 16 + tid] : 0.f;
        if (tid < 112) {
            int o = tid >> 4, c = tid & 15;
            float v;
            if (o == 0)      v = w_critic[g * 16 + c];
            else if (o < 4)  v = w_actor [(o - 1) * 128 + g * 16 + c];
            else             v = w_actor2[(o - 4) * 128 + g * 16 + c];
            hw_s[tid] = v;
        }
        if (g == 0 && tid == 0) {
            hb_s[0] = b_critic[0];
            hb_s[1] = b_actor[0];  hb_s[2] = b_actor[1];  hb_s[3] = b_actor[2];
            hb_s[4] = b_actor2[0]; hb_s[5] = b_actor2[1]; hb_s[6] = b_actor2[2];
        }
        __syncthreads();

        // g0 = W_hh @ hx + biases (off critical path, during H3 wait)
        float g0;
        {
            const float4* hp = (const float4*)(hx_s + p * 32);
            float s = 0.f;
            #pragma unroll
            for (int j = 0; j < 8; ++j) s += dot4(ah[j], hp[j]);
            s += __shfl_xor(s, 1); s += __shfl_xor(s, 2);
            g0 = s + bsum;
        }

        if (tid < 128) h3_s[tid] = recv(wsp + H3_OFF + tid);
        __syncthreads();

        { // h4: all 128 rows, redundant per G block (kills the H4 hop)
            const float4* hp = (const float4*)(h3_s + p4 * 64);
            float s = 0.f;
            #pragma unroll
            for (int j = 0; j < 16; ++j) s += dot4(a4[j], hp[j]);
            s += __shfl_xor(s, 1);
            if (p4 == 0) h4_s[r4] = lrelu(s + bb4);
        }
        __syncthreads();

        { // gates for 64 rows
            const float4* hp = (const float4*)(h4_s + p * 32);
            float s = 0.f;
            #pragma unroll
            for (int j = 0; j < 8; ++j) s += dot4(ai[j], hp[j]);
            s += __shfl_xor(s, 1); s += __shfl_xor(s, 2);
            if (p == 0) g_s[r] = g0 + s;   // r = gate*16 + cell
        }
        __syncthreads();

        if (tid < 16) {   // LSTM elementwise, 16 cells
            float ig = g_s[tid];
            float fg = g_s[16 + tid];
            float gg = g_s[32 + tid];
            float og = g_s[48 + tid];
            float c  = sigm(fg) * cxv + sigm(ig) * tanhf(gg);
            hn_s[tid] = sigm(og) * tanhf(c);
        }
        __syncthreads();

        if (tid < 7) {    // 7 head partials over this block's 16 cells
            const float* wc = hw_s + tid * 16;
            float s = 0.f;
            #pragma unroll
            for (int j = 0; j < 16; ++j) s += wc[j] * hn_s[j];
            if (g > 0) send(wsp + PT_OFF + g * 8 + tid, s);
            else       ps[tid * 8] = s + hb_s[tid];
        }

        if (g == 0) {
            if (tid < 56) {
                const int gg = (tid >> 3) + 1, h = tid & 7;
                if (h < 7) ps[h * 8 + gg] = recv(wsp + PT_OFF + gg * 8 + h);
            }
            __syncthreads();
            if (tid < 7) {
                const float* row = ps + tid * 8;
                float s = row[0] + row[1] + row[2] + row[3]
                        + row[4] + row[5] + row[6] + row[7];
                if (tid >= 1 && tid <= 3) s = s / (1.f + fabsf(s));
                out[tid] = s;
            }
        }
    }
}

extern "C" void kernel_launch(void* const* d_in, const int* in_sizes, int n_in,
                              void* d_out, int out_size, void* d_ws, size_t ws_size,
                              hipStream_t stream) {
    const float* x        = (const float*)d_in[0];
    const float* hx       = (const float*)d_in[1];
    const float* cx       = (const float*)d_in[2];
    const float* w1       = (const float*)d_in[3];
    const float* b1       = (const float*)d_in[4];
    const float* w2       = (const float*)d_in[5];
    const float* b2       = (const float*)d_in[6];
    const float* w3       = (const float*)d_in[7];
    const float* b3       = (const float*)d_in[8];
    const float* w4       = (const float*)d_in[9];
    const float* b4       = (const float*)d_in[10];
    const float* w_ih     = (const float*)d_in[11];
    const float* b_ih     = (const float*)d_in[12];
    const float* w_hh     = (const float*)d_in[13];
    const float* b_hh     = (const float*)d_in[14];
    const float* w_critic = (const float*)d_in[15];
    const float* b_critic = (const float*)d_in[16];
    const float* w_actor  = (const float*)d_in[17];
    const float* b_actor  = (const float*)d_in[18];
    const float* w_actor2 = (const float*)d_in[19];
    const float* b_actor2 = (const float*)d_in[20];
    float* out = (float*)d_out;
    unsigned long long* wsp = (unsigned long long*)d_ws;

    a3c_fwd<<<NB, TPB, 0, stream>>>(x, hx, cx, w1, b1, w2, b2, w3, b3, w4, b4,
                                    w_ih, b_ih, w_hh, b_hh,
                                    w_critic, b_critic, w_actor, b_actor,
                                    w_actor2, b_actor2, out, wsp);
}